// Round 4
// baseline (684.368 us; speedup 1.0000x reference)
//
#include <hip/hip_runtime.h>
#include <hip/hip_bf16.h>

#define E_EDGES 500000
#define NN 50000

typedef unsigned short u16;
typedef __attribute__((ext_vector_type(8))) short s16x8;
typedef __attribute__((ext_vector_type(4))) float f32x4;

#define WAITVM6()  asm volatile("s_waitcnt vmcnt(6)" ::: "memory")
#define WAITVM8()  asm volatile("s_waitcnt vmcnt(8)" ::: "memory")
#define WAITVM0()  asm volatile("s_waitcnt vmcnt(0)" ::: "memory")
#define WAITLGKM0() asm volatile("s_waitcnt lgkmcnt(0)" ::: "memory")
#define BAR() __builtin_amdgcn_s_barrier()
#define SCHED0() __builtin_amdgcn_sched_barrier(0)

__device__ __forceinline__ short f2bf(float f) {
    unsigned u = __builtin_bit_cast(unsigned, f);
    u += 0x7fffu + ((u >> 16) & 1u);
    return (short)(u >> 16);
}

__device__ __forceinline__ float lrelu(float x) { return x > 0.0f ? x : 0.01f * x; }

// async global->LDS, 16B per lane, dest = uniform base + lane*16
__device__ __forceinline__ void gll16(const float* g, const float* l) {
    __builtin_amdgcn_global_load_lds(
        (const __attribute__((address_space(1))) unsigned*)g,
        (__attribute__((address_space(3))) unsigned*)l, 16, 0, 0);
}

// read 8 fp32 from LDS, convert to bf16x8 (v_cvt_pk_bf16_f32 pairs)
__device__ __forceinline__ s16x8 cvtfrag(const float* p) {
    float4 a = *(const float4*)p;
    float4 b = *(const float4*)(p + 4);
    union { s16x8 v; __hip_bfloat162 h[4]; } u;
    u.h[0] = __float22bfloat162_rn(make_float2(a.x, a.y));
    u.h[1] = __float22bfloat162_rn(make_float2(a.z, a.w));
    u.h[2] = __float22bfloat162_rn(make_float2(b.x, b.y));
    u.h[3] = __float22bfloat162_rn(make_float2(b.z, b.w));
    return u.v;
}

// ---- weight prep: WT[g][n][k] = bf16(W_g[k][n]) ----
__global__ void kprep(const float* __restrict__ Wsrc, const float* __restrict__ Wtgt,
                      const float* __restrict__ Wedge, u16* __restrict__ WT) {
    int i = blockIdx.x * 256 + threadIdx.x;
    if (i >= 3 * 16384) return;
    int g = i >> 14, nk = i & 16383, n = nk >> 7, k = nk & 127;
    const float* W = (g == 0) ? Wsrc : (g == 1) ? Wtgt : Wedge;
    WT[i] = (u16)f2bf(W[k * 128 + n]);
}

// ---- K1: persistent, async-staged. 512 thr (8 waves), tile=32 rows, 96KB LDS dbuf.
// wave = (head = wv&3, mhalf = wv>>2). B frags in VGPR (96). ----
__global__ __launch_bounds__(512, 2) void k1(
    const float* __restrict__ recv, const float* __restrict__ send,
    const float* __restrict__ eattr, const int* __restrict__ sidx,
    const u16* __restrict__ WT, const float* __restrict__ attn,
    float* __restrict__ ez, float* __restrict__ denom)
{
    __shared__ float lA[2][3][32][128];   // 96 KB
    const int tid = threadIdx.x;
    const int lane = tid & 63, wv = tid >> 6;
    const int l15 = lane & 15, lg = (lane >> 4) & 3;
    const int head = wv & 3, mh = wv >> 2;

    const int b = blockIdx.x;
    const int start = b * 61 + min(b, 9);          // 15625 tiles over 256 blocks
    const int cnt = 61 + (b < 9 ? 1 : 0);

    // B fragments: bfr[g][kk][nn], head-local (cols head*32 .. +31)
    s16x8 bfr[3][4][2];
#pragma unroll
    for (int g = 0; g < 3; ++g)
#pragma unroll
        for (int kk = 0; kk < 4; ++kk)
#pragma unroll
            for (int nn = 0; nn < 2; ++nn)
                bfr[g][kk][nn] = *(const s16x8*)(WT + g * 16384 +
                    ((head * 2 + nn) * 16 + l15) * 128 + kk * 32 + lg * 8);

    const float av0 = attn[(head * 2 + 0) * 16 + l15];
    const float av1 = attn[(head * 2 + 1) * 16 + l15];

    const float* Xs0 = send; const float* Xs1 = recv; const float* Xs2 = eattr;

    const int hg = lane & 31;           // half-granule (16B) within row
    const int ro = lane >> 5;           // row parity within the 2-row inst

    // stage tile t (32 rows x 128 fp32 x 3 mats = 48KB, 48 wave-insts, 6/wave)
    auto stage = [&](int t, int buf) {
        int tileRow = t * 32;
#pragma unroll
        for (int q = 0; q < 6; ++q) {
            int j = wv + 8 * q;                  // 0..47 unique
            int g = j >> 4, i = j & 15;
            int r = 2 * i + ro;
            int gr = (hg >> 1) ^ (r & 15);       // pre-swizzled source granule
            const float* X = (g == 0) ? Xs0 : (g == 1) ? Xs1 : Xs2;
            const float* gp = X + (size_t)(tileRow + r) * 128 + gr * 8 + (hg & 1) * 4;
            gll16(gp, &lA[buf][g][2 * i][0]);
        }
    };

    int cur = 0;
    stage(start, 0);
    if (cnt > 1) stage(start + 1, 1);

    for (int ti = 0; ti < cnt; ++ti) {
        int t = start + ti;
        if (ti + 1 < cnt) { WAITVM6(); } else { WAITVM0(); }
        BAR(); SCHED0();

        int rbase = t * 32 + mh * 16 + lg * 4;
        int sv0 = sidx[rbase], sv1 = sidx[rbase + 1], sv2 = sidx[rbase + 2], sv3 = sidx[rbase + 3];

        f32x4 acc0 = (f32x4){0.f, 0.f, 0.f, 0.f};
        f32x4 acc1 = (f32x4){0.f, 0.f, 0.f, 0.f};
#pragma unroll
        for (int g = 0; g < 3; ++g) {
#pragma unroll
            for (int kk = 0; kk < 4; ++kk) {
                int gr = (kk * 4 + lg) ^ l15;
                s16x8 a = cvtfrag(&lA[cur][g][mh * 16 + l15][gr * 8]);
                acc0 = __builtin_amdgcn_mfma_f32_16x16x32_bf16(a, bfr[g][kk][0], acc0, 0, 0, 0);
                acc1 = __builtin_amdgcn_mfma_f32_16x16x32_bf16(a, bfr[g][kk][1], acc1, 0, 0, 0);
            }
        }
        WAITLGKM0(); SCHED0();
        BAR();

        float part[4];
#pragma unroll
        for (int j = 0; j < 4; ++j)
            part[j] = lrelu(acc0[j]) * av0 + lrelu(acc1[j]) * av1;
#pragma unroll
        for (int off = 1; off < 16; off <<= 1) {
#pragma unroll
            for (int j = 0; j < 4; ++j) part[j] += __shfl_xor(part[j], off, 64);
        }
        if (l15 == 0) {
#pragma unroll
            for (int j = 0; j < 4; ++j) {
                int r = rbase + j;
                float ezv = __expf(part[j]);
                ez[(size_t)r * 4 + head] = ezv;
                int s = (j == 0) ? sv0 : (j == 1) ? sv1 : (j == 2) ? sv2 : sv3;
                atomicAdd(&denom[(size_t)s * 4 + head], ezv);
            }
        }
        if (ti + 2 < cnt) stage(t + 2, cur);
        cur ^= 1;
    }
}

// ---- K2: persistent, async-staged. 256 thr (4 waves), tile=64 rows, 64KB LDS dbuf.
// wave = m-quarter (16 rows), all 128 cols. B frags in VGPR (128). a = ez/denom fused. ----
__global__ __launch_bounds__(256, 2) void k2(
    const float* __restrict__ recv, const int* __restrict__ ridx,
    const int* __restrict__ sidx, const u16* __restrict__ WTt,
    const float* __restrict__ ez, const float* __restrict__ denom,
    float* __restrict__ out0, float* __restrict__ out1)
{
    __shared__ float lA[2][64][128];   // 64 KB
    const int tid = threadIdx.x;
    const int lane = tid & 63, wv = tid >> 6;
    const int l15 = lane & 15, lg = (lane >> 4) & 3;

    const int b = blockIdx.x;
    const int start = b * 15 + min(b, 133);        // 7813 tiles over 512 blocks
    const int cnt = 15 + (b < 133 ? 1 : 0);

    s16x8 bfr[4][8];
#pragma unroll
    for (int kk = 0; kk < 4; ++kk)
#pragma unroll
        for (int n = 0; n < 8; ++n)
            bfr[kk][n] = *(const s16x8*)(WTt + (n * 16 + l15) * 128 + kk * 32 + lg * 8);

    const int hg = lane & 31;
    const int ro = lane >> 5;

    auto stage = [&](int t, int buf) {
        int tileRow = t * 64;
#pragma unroll
        for (int q = 0; q < 8; ++q) {
            int j = wv + 4 * q;                  // 0..31
            int r = 2 * j + ro;
            int gr = (hg >> 1) ^ (r & 15);
            int grow = min(tileRow + r, E_EDGES - 1);
            const float* gp = recv + (size_t)grow * 128 + gr * 8 + (hg & 1) * 4;
            gll16(gp, &lA[buf][2 * j][0]);
        }
    };

    int cur = 0;
    stage(start, 0);
    if (cnt > 1) stage(start + 1, 1);

    for (int ti = 0; ti < cnt; ++ti) {
        int t = start + ti;
        if (ti + 1 < cnt) { WAITVM8(); } else { WAITVM0(); }
        BAR(); SCHED0();

        int rbase = t * 64 + wv * 16 + lg * 4;
        int sv[4], rv[4]; float4 ezv[4];
#pragma unroll
        for (int j = 0; j < 4; ++j) {
            int r = min(rbase + j, E_EDGES - 1);
            sv[j] = sidx[r]; rv[j] = ridx[r];
            ezv[j] = *(const float4*)(ez + (size_t)r * 4);
        }

        f32x4 acc[8];
#pragma unroll
        for (int n = 0; n < 8; ++n) acc[n] = (f32x4){0.f, 0.f, 0.f, 0.f};
#pragma unroll
        for (int kk = 0; kk < 4; ++kk) {
            int gr = (kk * 4 + lg) ^ l15;
            s16x8 a = cvtfrag(&lA[cur][wv * 16 + l15][gr * 8]);
#pragma unroll
            for (int n = 0; n < 8; ++n)
                acc[n] = __builtin_amdgcn_mfma_f32_16x16x32_bf16(a, bfr[kk][n], acc[n], 0, 0, 0);
        }
        WAITLGKM0(); SCHED0();
        BAR();

#pragma unroll
        for (int j = 0; j < 4; ++j) {
            int r = rbase + j;
            if (r < E_EDGES) {
                float4 dn = *(const float4*)(denom + (size_t)sv[j] * 4);
                float ax = ezv[j].x / dn.x, ay = ezv[j].y / dn.y;
                float az = ezv[j].z / dn.z, aw = ezv[j].w / dn.w;
                float lo = 0.25f * (acc[0][j] * ax + acc[2][j] * ay +
                                    acc[4][j] * az + acc[6][j] * aw);
                float hi = 0.25f * (acc[1][j] * ax + acc[3][j] * ay +
                                    acc[5][j] * az + acc[7][j] * aw);
                out1[(size_t)r * 32 + l15] = lo;
                out1[(size_t)r * 32 + 16 + l15] = hi;
                atomicAdd(&out0[(size_t)rv[j] * 32 + l15], lo);
                atomicAdd(&out0[(size_t)rv[j] * 32 + 16 + l15], hi);
            }
        }
        if (ti + 2 < cnt) stage(t + 2, cur);
        cur ^= 1;
    }
}

extern "C" void kernel_launch(void* const* d_in, const int* in_sizes, int n_in,
                              void* d_out, int out_size, void* d_ws, size_t ws_size,
                              hipStream_t stream) {
    const float* recv  = (const float*)d_in[0];
    const float* send  = (const float*)d_in[1];
    const float* eattr = (const float*)d_in[2];
    const int*   sidx  = (const int*)d_in[3];
    const int*   ridx  = (const int*)d_in[4];
    const float* Wsrc  = (const float*)d_in[5];
    const float* Wtgt  = (const float*)d_in[6];
    const float* Wedge = (const float*)d_in[7];
    const float* attn  = (const float*)d_in[8];

    char* ws = (char*)d_ws;
    u16*   WT    = (u16*)ws;                         // 98304 B
    float* ez    = (float*)(ws + 131072);            // 8,000,000 B
    float* denom = (float*)(ws + 131072 + 8000000);  // 800,000 B

    float* out0 = (float*)d_out;                     // [N,32]
    float* out1 = out0 + (size_t)NN * 32;            // [E,32]

    hipMemsetAsync(denom, 0, (size_t)NN * 4 * sizeof(float), stream);
    hipMemsetAsync(out0, 0, (size_t)NN * 32 * sizeof(float), stream);

    kprep<<<192, 256, 0, stream>>>(Wsrc, Wtgt, Wedge, WT);

    k1<<<256, 512, 0, stream>>>(recv, send, eattr, sidx, WT, attn, ez, denom);
    k2<<<512, 256, 0, stream>>>(recv, ridx, sidx, WT + 16384, ez, denom, out0, out1);
}

// Round 5
// 619.967 us; speedup vs baseline: 1.1039x; 1.1039x over previous
//
#include <hip/hip_runtime.h>
#include <hip/hip_bf16.h>

#define E_EDGES 500000
#define NN 50000
#define NT 7813   // ceil(E/64)

typedef unsigned short u16;
typedef __attribute__((ext_vector_type(8))) short s16x8;
typedef __attribute__((ext_vector_type(4))) float f32x4;

__device__ __forceinline__ short f2bf(float f) {
    unsigned u = __builtin_bit_cast(unsigned, f);
    u += 0x7fffu + ((u >> 16) & 1u);
    return (short)(u >> 16);
}

__device__ __forceinline__ float lrelu(float x) { return x > 0.0f ? x : 0.01f * x; }

__device__ __forceinline__ s16x8 cvt8(float4 lo, float4 hi) {
    s16x8 w;
    w[0] = f2bf(lo.x); w[1] = f2bf(lo.y); w[2] = f2bf(lo.z); w[3] = f2bf(lo.w);
    w[4] = f2bf(hi.x); w[5] = f2bf(hi.y); w[6] = f2bf(hi.z); w[7] = f2bf(hi.w);
    return w;
}

// ---- weight prep: WT[g][n][k] = bf16(W_g[k][n]) ----
__global__ void kprep(const float* __restrict__ Wsrc, const float* __restrict__ Wtgt,
                      const float* __restrict__ Wedge, u16* __restrict__ WT) {
    int i = blockIdx.x * 256 + threadIdx.x;
    if (i >= 3 * 16384) return;
    int g = i >> 14, nk = i & 16383, n = nk >> 7, k = nk & 127;
    const float* W = (g == 0) ? Wsrc : (g == 1) ? Wtgt : Wedge;
    WT[i] = (u16)f2bf(W[k * 128 + n]);
}

// ---- K1: 64-row tile, ALL THREE matrices staged with one sync.
// q = s@Ws + r@Wt + e@We (t kept in separate accumulator);
// z = sum_c lrelu(q)*attn per head; ez=exp(z); denom atomicAdd. ----
__global__ __launch_bounds__(256, 3) void k1(
    const float* __restrict__ recv, const float* __restrict__ send,
    const float* __restrict__ eattr, const int* __restrict__ sidx,
    const u16* __restrict__ WT, const float* __restrict__ attn,
    float* __restrict__ ez, float* __restrict__ denom)
{
    __shared__ u16 lds[3][64][136];   // 52 KB -> 3 blocks/CU
    const int tid = threadIdx.x;
    const int lane = tid & 63, wv = tid >> 6;
    const int l15 = lane & 15, lg = (lane >> 4) & 3;
    const int row0 = blockIdx.x * 64;

    // stage: 3 mats x 64 rows x 16 granules(16B) = 3072 chunks, 12/thread,
    // all loads independent -> deep MLP
#pragma unroll
    for (int q = 0; q < 12; ++q) {
        int c = tid + 256 * q;
        int mat = c >> 10, rem = c & 1023;
        int row = rem >> 4, p = rem & 15;
        const float* X = (mat == 0) ? send : (mat == 1) ? recv : eattr;
        const float* src = X + (size_t)min(row0 + row, E_EDGES - 1) * 128 + p * 8;
        float4 v0 = *(const float4*)src;
        float4 v1 = *(const float4*)(src + 4);
        *(s16x8*)&lds[mat][row][p * 8] = cvt8(v0, v1);
    }
    __syncthreads();

    f32x4 as[8], at[8];
#pragma unroll
    for (int n = 0; n < 8; ++n) { as[n] = (f32x4){0,0,0,0}; at[n] = (f32x4){0,0,0,0}; }

#pragma unroll
    for (int g = 0; g < 3; ++g) {
#pragma unroll
        for (int kk = 0; kk < 4; ++kk) {
            s16x8 a = *(const s16x8*)&lds[g][wv * 16 + l15][kk * 32 + lg * 8];
#pragma unroll
            for (int n = 0; n < 8; ++n) {
                s16x8 b = *(const s16x8*)(WT + g * 16384 + (n * 16 + l15) * 128 + kk * 32 + lg * 8);
                if (g == 1) at[n] = __builtin_amdgcn_mfma_f32_16x16x32_bf16(a, b, at[n], 0, 0, 0);
                else        as[n] = __builtin_amdgcn_mfma_f32_16x16x32_bf16(a, b, as[n], 0, 0, 0);
            }
        }
    }

    float av[8];
#pragma unroll
    for (int n = 0; n < 8; ++n) av[n] = attn[n * 16 + l15];

#pragma unroll
    for (int h = 0; h < 4; ++h) {
        float part[4];
#pragma unroll
        for (int j = 0; j < 4; ++j) {
            float qe = as[2 * h][j] + at[2 * h][j];
            float qo = as[2 * h + 1][j] + at[2 * h + 1][j];
            part[j] = lrelu(qe) * av[2 * h] + lrelu(qo) * av[2 * h + 1];
        }
#pragma unroll
        for (int off = 1; off < 16; off <<= 1) {
#pragma unroll
            for (int j = 0; j < 4; ++j) part[j] += __shfl_xor(part[j], off, 64);
        }
        if (l15 == h) {
#pragma unroll
            for (int j = 0; j < 4; ++j) {
                int r = row0 + wv * 16 + lg * 4 + j;
                if (r < E_EDGES) {
                    float ezv = __expf(part[j]);
                    ez[(size_t)r * 4 + h] = ezv;
                    atomicAdd(&denom[(size_t)sidx[r] * 4 + h], ezv);
                }
            }
        }
    }
}

// ---- K2: t = r@Wt ; a = ez/denom[sidx] ; out1 = 0.25*sum_h t*a ; out0 atomic seg-sum.
// Same proven structure: reg-staged padded LDS, one sync. ----
__global__ __launch_bounds__(256, 4) void k2(
    const float* __restrict__ recv, const int* __restrict__ ridx,
    const int* __restrict__ sidx, const u16* __restrict__ WTt,
    const float* __restrict__ ez, const float* __restrict__ denom,
    float* __restrict__ out0, float* __restrict__ out1)
{
    __shared__ u16 lds[64][136];   // 17.4 KB
    const int tid = threadIdx.x;
    const int lane = tid & 63, wv = tid >> 6;
    const int l15 = lane & 15, lg = (lane >> 4) & 3;
    const int row0 = blockIdx.x * 64;

#pragma unroll
    for (int q = 0; q < 4; ++q) {
        int c = tid + 256 * q;
        int row = c >> 4, p = c & 15;
        const float* src = recv + (size_t)min(row0 + row, E_EDGES - 1) * 128 + p * 8;
        float4 v0 = *(const float4*)src;
        float4 v1 = *(const float4*)(src + 4);
        *(s16x8*)&lds[row][p * 8] = cvt8(v0, v1);
    }
    __syncthreads();

    f32x4 acc[8];
#pragma unroll
    for (int n = 0; n < 8; ++n) acc[n] = (f32x4){0,0,0,0};

#pragma unroll
    for (int kk = 0; kk < 4; ++kk) {
        s16x8 a = *(const s16x8*)&lds[wv * 16 + l15][kk * 32 + lg * 8];
#pragma unroll
        for (int n = 0; n < 8; ++n) {
            s16x8 b = *(const s16x8*)(WTt + (n * 16 + l15) * 128 + kk * 32 + lg * 8);
            acc[n] = __builtin_amdgcn_mfma_f32_16x16x32_bf16(a, b, acc[n], 0, 0, 0);
        }
    }

#pragma unroll
    for (int j = 0; j < 4; ++j) {
        int r = row0 + wv * 16 + lg * 4 + j;
        if (r < E_EDGES) {
            int s = sidx[r];
            float4 ezv = *(const float4*)(ez + (size_t)r * 4);
            float4 dn = *(const float4*)(denom + (size_t)s * 4);
            float a0 = ezv.x / dn.x, a1 = ezv.y / dn.y;
            float a2 = ezv.z / dn.z, a3 = ezv.w / dn.w;
            float lo = 0.25f * (acc[0][j] * a0 + acc[2][j] * a1 +
                                acc[4][j] * a2 + acc[6][j] * a3);
            float hi = 0.25f * (acc[1][j] * a0 + acc[3][j] * a1 +
                                acc[5][j] * a2 + acc[7][j] * a3);
            out1[(size_t)r * 32 + l15] = lo;
            out1[(size_t)r * 32 + 16 + l15] = hi;
            int rv = ridx[r];
            atomicAdd(&out0[(size_t)rv * 32 + l15], lo);
            atomicAdd(&out0[(size_t)rv * 32 + 16 + l15], hi);
        }
    }
}

extern "C" void kernel_launch(void* const* d_in, const int* in_sizes, int n_in,
                              void* d_out, int out_size, void* d_ws, size_t ws_size,
                              hipStream_t stream) {
    const float* recv  = (const float*)d_in[0];
    const float* send  = (const float*)d_in[1];
    const float* eattr = (const float*)d_in[2];
    const int*   sidx  = (const int*)d_in[3];
    const int*   ridx  = (const int*)d_in[4];
    const float* Wsrc  = (const float*)d_in[5];
    const float* Wtgt  = (const float*)d_in[6];
    const float* Wedge = (const float*)d_in[7];
    const float* attn  = (const float*)d_in[8];

    char* ws = (char*)d_ws;
    u16*   WT    = (u16*)ws;                         // 98304 B
    float* ez    = (float*)(ws + 131072);            // 8,000,000 B
    float* denom = (float*)(ws + 131072 + 8000000);  // 800,000 B

    float* out0 = (float*)d_out;                     // [N,32]
    float* out1 = out0 + (size_t)NN * 32;            // [E,32]

    hipMemsetAsync(denom, 0, (size_t)NN * 4 * sizeof(float), stream);
    hipMemsetAsync(out0, 0, (size_t)NN * 32 * sizeof(float), stream);

    kprep<<<192, 256, 0, stream>>>(Wsrc, Wtgt, Wedge, WT);

    k1<<<NT, 256, 0, stream>>>(recv, send, eattr, sidx, WT, attn, ez, denom);
    k2<<<NT, 256, 0, stream>>>(recv, ridx, sidx, WT + 16384, ez, denom, out0, out1);
}

// Round 6
// 393.662 us; speedup vs baseline: 1.7385x; 1.5749x over previous
//
#include <hip/hip_runtime.h>
#include <hip/hip_bf16.h>

#define E_EDGES 500000
#define NN 50000

typedef unsigned short u16;
typedef __attribute__((ext_vector_type(8))) short s16x8;
typedef __attribute__((ext_vector_type(4))) float f32x4;

#define BAR() __builtin_amdgcn_s_barrier()
#define SCHED0() __builtin_amdgcn_sched_barrier(0)
#define WAITLGKM0() asm volatile("s_waitcnt lgkmcnt(0)" ::: "memory")

__device__ __forceinline__ short f2bf(float f) {
    unsigned u = __builtin_bit_cast(unsigned, f);
    u += 0x7fffu + ((u >> 16) & 1u);
    return (short)(u >> 16);
}

__device__ __forceinline__ float lrelu(float x) { return x > 0.0f ? x : 0.01f * x; }

__device__ __forceinline__ s16x8 cvt8(float4 lo, float4 hi) {
    s16x8 w;
    w[0] = f2bf(lo.x); w[1] = f2bf(lo.y); w[2] = f2bf(lo.z); w[3] = f2bf(lo.w);
    w[4] = f2bf(hi.x); w[5] = f2bf(hi.y); w[6] = f2bf(hi.z); w[7] = f2bf(hi.w);
    return w;
}

// ---- weight prep: WT[g][n][k] = bf16(W_g[k][n]), g in {src, tgt, edge} ----
__global__ void kprep(const float* __restrict__ Wsrc, const float* __restrict__ Wtgt,
                      const float* __restrict__ Wedge, u16* __restrict__ WT) {
    int i = blockIdx.x * 256 + threadIdx.x;
    if (i >= 3 * 16384) return;
    int g = i >> 14, nk = i & 16383, n = nk >> 7, k = nk & 127;
    const float* W = (g == 0) ? Wsrc : (g == 1) ? Wtgt : Wedge;
    WT[i] = (u16)f2bf(W[k * 128 + n]);
}

// ---- K1: R0 structure + T14 async-stage split across the 3 matrix phases.
// Per phase g: [mfma(g-1) while loads(g) in flight] -> BAR -> commit(g) to LDS
// -> issue loads(g+1) -> lgkm0 -> BAR. Single-matrix HBM stream at any instant. ----
__global__ __launch_bounds__(256, 2) void k1(
    const float* __restrict__ recv, const float* __restrict__ send,
    const float* __restrict__ eattr, const int* __restrict__ sidx,
    const u16* __restrict__ WT, const float* __restrict__ attn,
    float* __restrict__ ez, float* __restrict__ denom)
{
    __shared__ u16 ldsA[128][136];
    __shared__ u16 ldsB[128][136];
    const int tid = threadIdx.x;
    const int lane = tid & 63, wv = tid >> 6;
    const int l15 = lane & 15, lg = (lane >> 4) & 3;
    const int blockRow = blockIdx.x * 128;

    const float* Xg[3] = {send, recv, eattr};

    f32x4 acc[2][8];
#pragma unroll
    for (int m = 0; m < 2; ++m)
#pragma unroll
        for (int n = 0; n < 8; ++n) acc[m][n] = (f32x4){0.f, 0.f, 0.f, 0.f};

    float4 ra[8][2];   // in-flight A chunks (64 VGPR)
    s16x8 rb[8];       // in-flight B chunks (32 VGPR)

    auto issue = [&](int g) {
        const float* X = Xg[g];
        const u16* Bg = WT + g * 16384;
#pragma unroll
        for (int q = 0; q < 8; ++q) {
            int idx = tid + 256 * q;
            int row = idx >> 4, gcol = (idx & 15) * 8;
            int ge = min(blockRow + row, E_EDGES - 1);
            const float* p = X + (size_t)ge * 128 + gcol;
            ra[q][0] = *(const float4*)p;
            ra[q][1] = *(const float4*)(p + 4);
        }
#pragma unroll
        for (int q = 0; q < 8; ++q) {
            int idx = tid + 256 * q;
            rb[q] = *(const s16x8*)(Bg + (idx >> 4) * 128 + (idx & 15) * 8);
        }
    };

    auto commit = [&]() {
#pragma unroll
        for (int q = 0; q < 8; ++q) {
            int idx = tid + 256 * q;
            int row = idx >> 4, gcol = (idx & 15) * 8;
            *(s16x8*)&ldsA[row][gcol] = cvt8(ra[q][0], ra[q][1]);
        }
#pragma unroll
        for (int q = 0; q < 8; ++q) {
            int idx = tid + 256 * q;
            *(s16x8*)&ldsB[idx >> 4][(idx & 15) * 8] = rb[q];
        }
    };

    auto mfma_g = [&]() {
#pragma unroll
        for (int kk = 0; kk < 4; ++kk) {
            int k0 = kk * 32 + lg * 8;
            s16x8 a0 = *(const s16x8*)&ldsA[wv * 32 + l15][k0];
            s16x8 a1 = *(const s16x8*)&ldsA[wv * 32 + 16 + l15][k0];
#pragma unroll
            for (int n = 0; n < 8; ++n) {
                s16x8 b = *(const s16x8*)&ldsB[n * 16 + l15][k0];
                acc[0][n] = __builtin_amdgcn_mfma_f32_16x16x32_bf16(a0, b, acc[0][n], 0, 0, 0);
                acc[1][n] = __builtin_amdgcn_mfma_f32_16x16x32_bf16(a1, b, acc[1][n], 0, 0, 0);
            }
        }
    };

    issue(0);
#pragma unroll
    for (int g = 0; g < 3; ++g) {
        if (g) { mfma_g(); SCHED0(); }   // compute g-1 while loads(g) stream in
        BAR();                            // all waves done reading LDS of g-1
        commit();                         // vmcnt wait (compiler) + cvt + ds_write
        if (g < 2) issue(g + 1);          // fire next phase's loads early
        SCHED0();
        WAITLGKM0();                      // ds_writes drained (vmcnt untouched)
        BAR();
    }
    mfma_g();                             // g = 2

    float av[8];
#pragma unroll
    for (int n = 0; n < 8; ++n) av[n] = attn[n * 16 + l15];

#pragma unroll
    for (int m = 0; m < 2; ++m) {
#pragma unroll
        for (int h = 0; h < 4; ++h) {
            float part[4];
#pragma unroll
            for (int j = 0; j < 4; ++j)
                part[j] = lrelu(acc[m][2 * h][j]) * av[2 * h] +
                          lrelu(acc[m][2 * h + 1][j]) * av[2 * h + 1];
#pragma unroll
            for (int off = 1; off < 16; off <<= 1) {
#pragma unroll
                for (int j = 0; j < 4; ++j) part[j] += __shfl_xor(part[j], off, 64);
            }
            if (l15 == h) {
#pragma unroll
                for (int j = 0; j < 4; ++j) {
                    int r = blockRow + wv * 32 + m * 16 + lg * 4 + j;
                    if (r < E_EDGES) {
                        float ezv = __expf(part[j]);
                        ez[(size_t)r * 4 + h] = ezv;
                        atomicAdd(&denom[(size_t)sidx[r] * 4 + h], ezv);
                    }
                }
            }
        }
    }
}

// ---- shared staging helpers (R0, proven in k2) ----
__device__ __forceinline__ void stage_A(const float* __restrict__ X, int blockRow,
                                        u16 (*ldsA)[136], int tid) {
#pragma unroll
    for (int it = 0; it < 8; ++it) {
        int chunk = it * 256 + tid;
        int row = chunk >> 4, kc = (chunk & 15) << 3;
        int ge = blockRow + row;
        float4 v0 = {0.f, 0.f, 0.f, 0.f}, v1 = {0.f, 0.f, 0.f, 0.f};
        if (ge < E_EDGES) {
            const float* p = X + (size_t)ge * 128 + kc;
            v0 = *(const float4*)p;
            v1 = *(const float4*)(p + 4);
        }
        *(s16x8*)&ldsA[row][kc] = cvt8(v0, v1);
    }
}

__device__ __forceinline__ void stage_B(const u16* __restrict__ WTg,
                                        u16 (*ldsB)[136], int tid) {
#pragma unroll
    for (int it = 0; it < 8; ++it) {
        int chunk = it * 256 + tid;
        int n = chunk >> 4, kc = (chunk & 15) << 3;
        *(s16x8*)&ldsB[n][kc] = *(const s16x8*)(WTg + n * 128 + kc);
    }
}

// ---- K_a: a = ez / denom[sender] (in place) ----
__global__ void ka(float* __restrict__ eza, const float* __restrict__ denom,
                   const int* __restrict__ sidx) {
    int e = blockIdx.x * 256 + threadIdx.x;
    if (e >= E_EDGES) return;
    float4 z = *(float4*)(eza + (size_t)e * 4);
    int s = sidx[e];
    float4 d = *(const float4*)(denom + (size_t)s * 4);
    z.x /= d.x; z.y /= d.y; z.z /= d.z; z.w /= d.w;
    *(float4*)(eza + (size_t)e * 4) = z;
}

// ---- K2: EXACT R0 structure (proven ~3.8 TB/s) ----
__global__ __launch_bounds__(256, 2) void k2(
    const float* __restrict__ recv, const int* __restrict__ ridx,
    const u16* __restrict__ WTt, const float* __restrict__ a,
    float* __restrict__ out0, float* __restrict__ out1)
{
    __shared__ u16 ldsA[128][136];
    __shared__ u16 ldsB[128][136];
    int tid = threadIdx.x;
    int lane = tid & 63, wv = tid >> 6;
    int l15 = lane & 15, lg = lane >> 4;
    int blockRow = blockIdx.x * 128;

    f32x4 acc[2][8];
#pragma unroll
    for (int m = 0; m < 2; ++m)
#pragma unroll
        for (int n = 0; n < 8; ++n) acc[m][n] = (f32x4){0.f, 0.f, 0.f, 0.f};

    stage_A(recv, blockRow, ldsA, tid);
    stage_B(WTt, ldsB, tid);
    __syncthreads();

#pragma unroll
    for (int kk = 0; kk < 4; ++kk) {
        int k0 = kk * 32 + lg * 8;
        s16x8 a0 = *(const s16x8*)&ldsA[wv * 32 + l15][k0];
        s16x8 a1 = *(const s16x8*)&ldsA[wv * 32 + 16 + l15][k0];
#pragma unroll
        for (int n = 0; n < 8; ++n) {
            s16x8 b = *(const s16x8*)&ldsB[n * 16 + l15][k0];
            acc[0][n] = __builtin_amdgcn_mfma_f32_16x16x32_bf16(a0, b, acc[0][n], 0, 0, 0);
            acc[1][n] = __builtin_amdgcn_mfma_f32_16x16x32_bf16(a1, b, acc[1][n], 0, 0, 0);
        }
    }

#pragma unroll
    for (int m = 0; m < 2; ++m) {
#pragma unroll
        for (int j = 0; j < 4; ++j) {
            int r = blockRow + wv * 32 + m * 16 + lg * 4 + j;
            if (r < E_EDGES) {
                float4 av = *(const float4*)(a + (size_t)r * 4);
                float lo = 0.25f * (acc[m][0][j] * av.x + acc[m][2][j] * av.y +
                                    acc[m][4][j] * av.z + acc[m][6][j] * av.w);
                float hi = 0.25f * (acc[m][1][j] * av.x + acc[m][3][j] * av.y +
                                    acc[m][5][j] * av.z + acc[m][7][j] * av.w);
                out1[(size_t)r * 32 + l15] = lo;
                out1[(size_t)r * 32 + 16 + l15] = hi;
                int rv = ridx[r];
                atomicAdd(&out0[(size_t)rv * 32 + l15], lo);
                atomicAdd(&out0[(size_t)rv * 32 + 16 + l15], hi);
            }
        }
    }
}

extern "C" void kernel_launch(void* const* d_in, const int* in_sizes, int n_in,
                              void* d_out, int out_size, void* d_ws, size_t ws_size,
                              hipStream_t stream) {
    const float* recv  = (const float*)d_in[0];
    const float* send  = (const float*)d_in[1];
    const float* eattr = (const float*)d_in[2];
    const int*   sidx  = (const int*)d_in[3];
    const int*   ridx  = (const int*)d_in[4];
    const float* Wsrc  = (const float*)d_in[5];
    const float* Wtgt  = (const float*)d_in[6];
    const float* Wedge = (const float*)d_in[7];
    const float* attn  = (const float*)d_in[8];

    char* ws = (char*)d_ws;
    u16*   WT    = (u16*)ws;                         // 98304 B
    float* ez    = (float*)(ws + 131072);            // 8,000,000 B
    float* denom = (float*)(ws + 131072 + 8000000);  // 800,000 B

    float* out0 = (float*)d_out;                     // [N,32]
    float* out1 = out0 + (size_t)NN * 32;            // [E,32]

    hipMemsetAsync(denom, 0, (size_t)NN * 4 * sizeof(float), stream);
    hipMemsetAsync(out0, 0, (size_t)NN * 32 * sizeof(float), stream);

    kprep<<<192, 256, 0, stream>>>(Wsrc, Wtgt, Wedge, WT);

    int nb = (E_EDGES + 127) / 128;  // 3907
    k1<<<nb, 256, 0, stream>>>(recv, send, eattr, sidx, WT, attn, ez, denom);
    ka<<<(E_EDGES + 255) / 256, 256, 0, stream>>>(ez, denom, sidx);
    k2<<<nb, 256, 0, stream>>>(recv, ridx, WT + 16384, ez, out0, out1);
}